// Round 7
// baseline (499.958 us; speedup 1.0000x reference)
//
#include <hip/hip_runtime.h>

// GCN 2-layer on MI355X — Round 7: two-level (dst-part, src-part) tile sort +
// LDS-staged streaming aggregation. No random global gathers anywhere.
//
// g[j] = x[j]*dinv[j].  layer1: agg[i]=dinv[i]*(sum g[src]+g[i])@W1+b1
// h = relu(agg); hs2 = (h@W2)*dinv;  out[i] = dinv[i]*(sum hs2[src]+hs2[i])+b2
//
// Pass A: sort edges by dp = dst>>11 (P=98 buckets), packed = (ld<<18)|src.
// Pass B: within each dp range, sort by sp = src>>11 -> 98x98 tiles,
//         packed2 = (ld<<11)|ls.  tileStart[dp*P+sp] marks tile boundaries.
// Agg:    block = (chunk, dp); for each sp window: stage g/hs2 window into
//         LDS (coalesced), serve edge gathers from LDS, acc in LDS; dump
//         partials; per-node reduce with fused dense epilogue.
//
// ws: colTotal|colStart|cnt2[P*P*8]|tileStart[P*P+1]|cntmat1[B1*P]|
//     packed[E] (reused as partial after pass B) | packed2[E] | dinv|g|hs2

#define EPB   8192   // edges per pass-A bucket block
#define PART  2048   // nodes per partition
#define LPBIT 11
#define SRCB  18     // src bits in pass-A packed
#define B2    8      // pass-B sub-blocks per dp
#define NC1   14     // agg1 chunks per dp (7 windows each when P=98)
#define NC2   7      // agg2 chunks per dp (14 windows each)

// ---------------- Pass A (unchanged machinery) ----------------

__global__ __launch_bounds__(512) void bucket_count_kernel(
    const int* __restrict__ dst, int* __restrict__ cntmat, int E, int P) {
    __shared__ int cnt[128];
    int tid = threadIdx.x;
    if (tid < 128) cnt[tid] = 0;
    __syncthreads();
    int base = blockIdx.x * EPB;
    #pragma unroll
    for (int k = 0; k < EPB; k += 512) {
        int e = base + k + tid;
        if (e < E) atomicAdd(&cnt[dst[e] >> LPBIT], 1);
    }
    __syncthreads();
    int* row = cntmat + (size_t)blockIdx.x * P;
    if (tid < P) row[tid] = cnt[tid];
}

__global__ __launch_bounds__(256) void col_scan_kernel(
    int* __restrict__ cntmat, int* __restrict__ colTotal, int B, int P) {
    __shared__ int sdata[256];
    int p = blockIdx.x, tid = threadIdx.x;
    int v[4];
    int s = 0;
    #pragma unroll
    for (int k = 0; k < 4; k++) {
        int b = tid * 4 + k;
        v[k] = (b < B) ? cntmat[(size_t)b * P + p] : 0;
        s += v[k];
    }
    int x = s;
    sdata[tid] = x;
    __syncthreads();
    for (int off = 1; off < 256; off <<= 1) {
        int t = (tid >= off) ? sdata[tid - off] : 0;
        __syncthreads();
        x += t;
        sdata[tid] = x;
        __syncthreads();
    }
    int run = x - s;
    #pragma unroll
    for (int k = 0; k < 4; k++) {
        int b = tid * 4 + k;
        if (b < B) cntmat[(size_t)b * P + p] = run;
        run += v[k];
    }
    if (tid == 255) colTotal[p] = x;
}

__global__ __launch_bounds__(256) void total_scan_kernel(
    const int* __restrict__ colTotal, int* __restrict__ colStart,
    int P, int E) {
    __shared__ int sdata[256];
    int tid = threadIdx.x;
    int v[4];
    int s = 0;
    #pragma unroll
    for (int k = 0; k < 4; k++) {
        int i = tid * 4 + k;
        v[k] = (i < P) ? colTotal[i] : 0;
        s += v[k];
    }
    int x = s;
    sdata[tid] = x;
    __syncthreads();
    for (int off = 1; off < 256; off <<= 1) {
        int t = (tid >= off) ? sdata[tid - off] : 0;
        __syncthreads();
        x += t;
        sdata[tid] = x;
        __syncthreads();
    }
    int run = x - s;
    #pragma unroll
    for (int k = 0; k < 4; k++) {
        int i = tid * 4 + k;
        if (i < P) colStart[i] = run;
        run += v[k];
    }
    if (tid == 0) colStart[P] = E;
}

__global__ __launch_bounds__(512) void bucket_scatter_kernel(
    const int* __restrict__ src, const int* __restrict__ dst,
    const int* __restrict__ cntmat, const int* __restrict__ colStart,
    unsigned* __restrict__ packed, int E, int P) {
    __shared__ int cur[128];
    int tid = threadIdx.x;
    if (tid < P) cur[tid] = colStart[tid] + cntmat[(size_t)blockIdx.x * P + tid];
    __syncthreads();
    int base = blockIdx.x * EPB;
    #pragma unroll
    for (int k = 0; k < EPB; k += 512) {
        int e = base + k + tid;
        if (e < E) {
            int d = dst[e];
            int pos = atomicAdd(&cur[d >> LPBIT], 1);
            packed[pos] = ((unsigned)(d & (PART - 1)) << SRCB) | (unsigned)src[e];
        }
    }
}

// ---------------- Pass B: per-dp sort by src partition ----------------

// block = (dp, b): histogram sp over sub-range b of dp's edge list.
// cnt2 layout: [(dp*P + sp)*B2 + b].
__global__ __launch_bounds__(512) void count2_kernel(
    const unsigned* __restrict__ packed, const int* __restrict__ colStart,
    int* __restrict__ cnt2, int P) {
    __shared__ int cnt[128];
    int tid = threadIdx.x;
    int dp = blockIdx.x >> 3, b = blockIdx.x & (B2 - 1);
    if (tid < 128) cnt[tid] = 0;
    __syncthreads();
    int s0 = colStart[dp], len = colStart[dp + 1] - s0;
    int lo = s0 + (int)(((long long)len * b) / B2);
    int hi = s0 + (int)(((long long)len * (b + 1)) / B2);
    for (int i = lo + tid; i < hi; i += 512)
        atomicAdd(&cnt[(packed[i] & ((1u << SRCB) - 1)) >> LPBIT], 1);
    __syncthreads();
    if (tid < P) cnt2[((size_t)dp * P + tid) * B2 + b] = cnt[tid];
}

// One block per dp: exclusive scan of the P*B2 (sp-major) counts; fold in the
// dp base so cnt2 becomes absolute cursors; emit tileStart[dp*P+sp].
__global__ __launch_bounds__(256) void scan2b_kernel(
    int* __restrict__ cnt2, const int* __restrict__ colStart,
    int* __restrict__ tileStart, int P, int E) {
    __shared__ int sdata[256];
    int dp = blockIdx.x, tid = threadIdx.x;
    int M = P * B2;           // 784
    int* row = cnt2 + (size_t)dp * M;
    int base = colStart[dp];
    int v[4];
    int s = 0;
    #pragma unroll
    for (int k = 0; k < 4; k++) {
        int idx = tid * 4 + k;
        v[k] = (idx < M) ? row[idx] : 0;
        s += v[k];
    }
    int x = s;
    sdata[tid] = x;
    __syncthreads();
    for (int off = 1; off < 256; off <<= 1) {
        int t = (tid >= off) ? sdata[tid - off] : 0;
        __syncthreads();
        x += t;
        sdata[tid] = x;
        __syncthreads();
    }
    int run = x - s;
    #pragma unroll
    for (int k = 0; k < 4; k++) {
        int idx = tid * 4 + k;
        if (idx < M) {
            row[idx] = base + run;
            if ((idx & (B2 - 1)) == 0)
                tileStart[dp * P + (idx >> 3)] = base + run;
        }
        run += v[k];
    }
    if (dp == P - 1 && tid == 0) tileStart[P * P] = E;
}

// block = (dp, b): scatter sub-range into (dp,sp) tiles via LDS cursors.
// packed2 = (localdst<<11)|localsrc.
__global__ __launch_bounds__(512) void scatter2b_kernel(
    const unsigned* __restrict__ packed, const int* __restrict__ colStart,
    const int* __restrict__ cnt2, unsigned* __restrict__ packed2, int P) {
    __shared__ int cur[128];
    int tid = threadIdx.x;
    int dp = blockIdx.x >> 3, b = blockIdx.x & (B2 - 1);
    if (tid < P) cur[tid] = cnt2[((size_t)dp * P + tid) * B2 + b];
    __syncthreads();
    int s0 = colStart[dp], len = colStart[dp + 1] - s0;
    int lo = s0 + (int)(((long long)len * b) / B2);
    int hi = s0 + (int)(((long long)len * (b + 1)) / B2);
    for (int i = lo + tid; i < hi; i += 512) {
        unsigned w = packed[i];
        unsigned srcv = w & ((1u << SRCB) - 1);
        int sp = (int)(srcv >> LPBIT);
        int pos = atomicAdd(&cur[sp], 1);
        packed2[pos] = ((w >> SRCB) << LPBIT) | (srcv & (PART - 1));
    }
}

// ---------------- Node-side ----------------

// One block per dp: degree hist over packed2 range -> dinv, g = x*dinv.
__global__ __launch_bounds__(512) void dinv_g_kernel(
    const unsigned* __restrict__ packed2, const int* __restrict__ colStart,
    const float* __restrict__ x, float* __restrict__ dinv,
    float* __restrict__ g, int n) {
    __shared__ int hist[PART];
    int p = blockIdx.x, tid = threadIdx.x;
    for (int i = tid; i < PART; i += 512) hist[i] = 0;
    __syncthreads();
    int s0 = colStart[p], s1 = colStart[p + 1];
    for (int i = s0 + tid; i < s1; i += 512)
        atomicAdd(&hist[packed2[i] >> LPBIT], 1);
    __syncthreads();
    const float2* xp = (const float2*)x;
    float2* gp = (float2*)g;
    for (int j = tid; j < PART; j += 512) {
        int node = (p << LPBIT) + j;
        if (node < n) {
            float d = rsqrtf((float)hist[j] + 1.0f);  // +1 self-loop
            dinv[node] = d;
            float2 xv = xp[node];
            gp[node] = make_float2(xv.x * d, xv.y * d);
        }
    }
}

// ---------------- Aggregation (LDS-staged windows) ----------------

// block = (c, dp): chunk c covers sp windows [c*W, ...). Stage g window in
// LDS, gather from LDS, accumulate in LDS, dump partial.
__global__ __launch_bounds__(512) void agg1_kernel(
    const unsigned* __restrict__ packed2, const int* __restrict__ tileStart,
    const float* __restrict__ g, float* __restrict__ partial, int P) {
    __shared__ float2 stage[PART];
    __shared__ float accx[PART];
    __shared__ float accy[PART];
    int tid = threadIdx.x;
    int c = blockIdx.x, dp = blockIdx.y;
    for (int j = tid; j < PART; j += 512) { accx[j] = 0.0f; accy[j] = 0.0f; }
    int W = (P + NC1 - 1) / NC1;  // 7
    int sp0 = c * W, sp1 = min(sp0 + W, P);
    const float2* gp = (const float2*)g;
    for (int sp = sp0; sp < sp1; sp++) {
        __syncthreads();
        int nb = sp << LPBIT;
        for (int j = tid; j < PART; j += 512) stage[j] = gp[nb + j];
        __syncthreads();
        int t0 = tileStart[dp * P + sp], t1 = tileStart[dp * P + sp + 1];
        for (int i = t0 + tid; i < t1; i += 512) {
            unsigned w = packed2[i];
            int ls = (int)(w & (PART - 1));
            int ld = (int)(w >> LPBIT);
            float2 v = stage[ls];
            atomicAdd(&accx[ld], v.x);
            atomicAdd(&accy[ld], v.y);
        }
    }
    __syncthreads();
    float2* pp = (float2*)partial + ((size_t)dp * NC1 + c) * PART;
    for (int j = tid; j < PART; j += 512)
        pp[j] = make_float2(accx[j], accy[j]);
}

// Per-node reduce + fused dense epilogue: W1 + b1 + ReLU + W2 + dinv -> hs2.
__global__ __launch_bounds__(256) void reduce1_kernel(
    const float* __restrict__ partial, const float* __restrict__ g,
    const float* __restrict__ dinv, const float* __restrict__ W1,
    const float* __restrict__ b1, const float* __restrict__ W2,
    float* __restrict__ hs2, int n) {
    int i = blockIdx.x * 256 + threadIdx.x;
    if (i >= n) return;
    int p = i >> LPBIT, ld = i & (PART - 1);
    const float2* pp = (const float2*)partial;
    float s0 = 0.0f, s1 = 0.0f;
    #pragma unroll
    for (int c = 0; c < NC1; c++) {
        float2 v = pp[((size_t)p * NC1 + c) * PART + ld];
        s0 += v.x;
        s1 += v.y;
    }
    float2 gv = ((const float2*)g)[i];
    float d = dinv[i];
    s0 = (s0 + gv.x) * d;
    s1 = (s1 + gv.y) * d;
    float h[8];
    #pragma unroll
    for (int f = 0; f < 8; f++)
        h[f] = fmaxf(s0 * W1[f] + s1 * W1[8 + f] + b1[f], 0.0f);
    float oc[4];
    #pragma unroll
    for (int k = 0; k < 4; k++) {
        float a = 0.0f;
        #pragma unroll
        for (int f = 0; f < 8; f++) a += h[f] * W2[4 * f + k];
        oc[k] = a * d;
    }
    float4 o;
    o.x = oc[0]; o.y = oc[1]; o.z = oc[2]; o.w = oc[3];
    *(float4*)(hs2 + 4 * (size_t)i) = o;
}

// block = (c, dp): LDS-staged hs2 windows; 64 KB LDS -> 2 blocks/CU.
__global__ __launch_bounds__(512) void agg2_kernel(
    const unsigned* __restrict__ packed2, const int* __restrict__ tileStart,
    const float* __restrict__ hs2, float* __restrict__ partial, int P) {
    __shared__ float4 stage[PART];
    __shared__ float acc0[PART], acc1[PART], acc2[PART], acc3[PART];
    int tid = threadIdx.x;
    int c = blockIdx.x, dp = blockIdx.y;
    for (int j = tid; j < PART; j += 512) {
        acc0[j] = 0.0f; acc1[j] = 0.0f; acc2[j] = 0.0f; acc3[j] = 0.0f;
    }
    int W = (P + NC2 - 1) / NC2;  // 14
    int sp0 = c * W, sp1 = min(sp0 + W, P);
    const float4* hp = (const float4*)hs2;
    for (int sp = sp0; sp < sp1; sp++) {
        __syncthreads();
        int nb = sp << LPBIT;
        for (int j = tid; j < PART; j += 512) stage[j] = hp[nb + j];
        __syncthreads();
        int t0 = tileStart[dp * P + sp], t1 = tileStart[dp * P + sp + 1];
        for (int i = t0 + tid; i < t1; i += 512) {
            unsigned w = packed2[i];
            int ls = (int)(w & (PART - 1));
            int ld = (int)(w >> LPBIT);
            float4 v = stage[ls];
            atomicAdd(&acc0[ld], v.x);
            atomicAdd(&acc1[ld], v.y);
            atomicAdd(&acc2[ld], v.z);
            atomicAdd(&acc3[ld], v.w);
        }
    }
    __syncthreads();
    float4* pp = (float4*)partial + ((size_t)dp * NC2 + c) * PART;
    for (int j = tid; j < PART; j += 512) {
        float4 v;
        v.x = acc0[j]; v.y = acc1[j]; v.z = acc2[j]; v.w = acc3[j];
        pp[j] = v;
    }
}

__global__ __launch_bounds__(256) void reduce2_kernel(
    const float* __restrict__ partial, const float* __restrict__ hs2,
    const float* __restrict__ dinv, const float* __restrict__ b2,
    float* __restrict__ out, int n) {
    int i = blockIdx.x * 256 + threadIdx.x;
    if (i >= n) return;
    int p = i >> LPBIT, ld = i & (PART - 1);
    const float4* pp = (const float4*)partial;
    float4 s = make_float4(0.f, 0.f, 0.f, 0.f);
    #pragma unroll
    for (int c = 0; c < NC2; c++) {
        float4 v = pp[((size_t)p * NC2 + c) * PART + ld];
        s.x += v.x; s.y += v.y; s.z += v.z; s.w += v.w;
    }
    float4 h = *(const float4*)(hs2 + 4 * (size_t)i);
    float d = dinv[i];
    float4 o;
    o.x = d * (s.x + h.x) + b2[0];
    o.y = d * (s.y + h.y) + b2[1];
    o.z = d * (s.z + h.z) + b2[2];
    o.w = d * (s.w + h.w) + b2[3];
    *(float4*)(out + 4 * (size_t)i) = o;
}

extern "C" void kernel_launch(void* const* d_in, const int* in_sizes, int n_in,
                              void* d_out, int out_size, void* d_ws, size_t ws_size,
                              hipStream_t stream) {
    const float* x   = (const float*)d_in[0];
    const int*   ei  = (const int*)d_in[1];
    const float* W1  = (const float*)d_in[2];
    const float* b1  = (const float*)d_in[3];
    const float* W2  = (const float*)d_in[4];
    const float* b2  = (const float*)d_in[5];
    float* out = (float*)d_out;

    const int n = in_sizes[0] / 2;  // x is [N,2]
    const int E = in_sizes[1] / 2;  // edge_index is [2,E]
    const int* src = ei;
    const int* dst = ei + E;

    const int P  = (n + PART - 1) >> LPBIT;  // 98
    const int B1 = (E + EPB - 1) / EPB;      // 782

    int* ws = (int*)d_ws;
    int* colTotal = ws;                                          // 1024
    int* colStart = ws + 1024;                                   // 1024
    int* cnt2     = ws + 2048;                                   // P*P*B2
    size_t c2sz = (((size_t)P * P * B2) + 3) & ~(size_t)3;
    int* tileStart = cnt2 + c2sz;                                // P*P+1
    size_t tssz = (((size_t)P * P + 1) + 3) & ~(size_t)3;
    int* cntmat1  = tileStart + tssz;                            // B1*P
    size_t cmsz = (((size_t)B1 * P) + 3) & ~(size_t)3;
    unsigned* packed  = (unsigned*)(cntmat1 + cmsz);             // E
    unsigned* packed2 = packed + E;                              // E
    size_t nd = ((size_t)n + PART + 3) & ~(size_t)3;
    float* dinv = (float*)(packed2 + E);                         // nd
    float* g    = dinv + nd;                                     // 2*nd
    float* hs2  = g + 2 * nd;                                    // 4*nd
    float* partial = (float*)packed;  // packed dead after pass B

    bucket_count_kernel  <<<B1, 512, 0, stream>>>(dst, cntmat1, E, P);
    col_scan_kernel      <<<P, 256, 0, stream>>>(cntmat1, colTotal, B1, P);
    total_scan_kernel    <<<1, 256, 0, stream>>>(colTotal, colStart, P, E);
    bucket_scatter_kernel<<<B1, 512, 0, stream>>>(src, dst, cntmat1, colStart, packed, E, P);
    count2_kernel        <<<P * B2, 512, 0, stream>>>(packed, colStart, cnt2, P);
    scan2b_kernel        <<<P, 256, 0, stream>>>(cnt2, colStart, tileStart, P, E);
    scatter2b_kernel     <<<P * B2, 512, 0, stream>>>(packed, colStart, cnt2, packed2, P);
    dinv_g_kernel        <<<P, 512, 0, stream>>>(packed2, colStart, x, dinv, g, n);
    {
        dim3 grid1(NC1, P);
        agg1_kernel<<<grid1, 512, 0, stream>>>(packed2, tileStart, g, partial, P);
    }
    reduce1_kernel       <<<(n + 255) / 256, 256, 0, stream>>>(partial, g, dinv, W1, b1, W2, hs2, n);
    {
        dim3 grid2(NC2, P);
        agg2_kernel<<<grid2, 512, 0, stream>>>(packed2, tileStart, hs2, partial, P);
    }
    reduce2_kernel       <<<(n + 255) / 256, 256, 0, stream>>>(partial, hs2, dinv, b2, out, n);
}

// Round 8
// 372.511 us; speedup vs baseline: 1.3421x; 1.3421x over previous
//
#include <hip/hip_runtime.h>

// GCN 2-layer on MI355X — Round 8: full CSR via two-level LDS bucket sort,
// ZERO per-edge atomics in aggregation (register accumulation per dst node).
//
// g[j] = x[j]*dinv[j].  layer1: hs2[i] via relu(dinv*(sum g)+b1)@W2*dinv
// layer2: out[i] = dinv[i]*(sum hs2[src]+hs2[i]) + b2
//
// Pass A: bucket by dp = dst>>11 (P=98), packed = (ld<<18)|src.
// Pass C: per-dp counting sort over ld (2048 buckets, 8 sub-blocks/dp via
//         cnt2[dp][ld][b] matrix + per-dp scan) -> srcsorted (CSR) + rowptr.
// Agg:    thread = node, gather g/hs2 (L2-resident), register acc, fused
//         dense epilogues. No atomics, no partials.
//
// ws: colTotal|colStart|cntmatA[B1*P]|rowptr[n+4]|packed[E]|srcsorted[E]|
//     cnt2[P*2048*8] (reused after pass C as dinv|g|hs2)   ~59 MB

#define EPB   8192   // edges per pass-A block
#define PART  2048   // nodes per partition
#define LPBIT 11
#define SRCB  18     // src bits in packed
#define BC    8      // pass-C sub-blocks per dp

// ---------------- Pass A ----------------

__global__ __launch_bounds__(512) void countA_kernel(
    const int* __restrict__ dst, int* __restrict__ cntmat, int E, int P) {
    __shared__ int cnt[128];
    int tid = threadIdx.x;
    if (tid < 128) cnt[tid] = 0;
    __syncthreads();
    int base = blockIdx.x * EPB;
    #pragma unroll
    for (int k = 0; k < EPB; k += 512) {
        int e = base + k + tid;
        if (e < E) atomicAdd(&cnt[dst[e] >> LPBIT], 1);
    }
    __syncthreads();
    int* row = cntmat + (size_t)blockIdx.x * P;
    if (tid < P) row[tid] = cnt[tid];
}

__global__ __launch_bounds__(256) void colscanA_kernel(
    int* __restrict__ cntmat, int* __restrict__ colTotal, int B, int P) {
    __shared__ int sdata[256];
    int p = blockIdx.x, tid = threadIdx.x;
    int v[4];
    int s = 0;
    #pragma unroll
    for (int k = 0; k < 4; k++) {
        int b = tid * 4 + k;
        v[k] = (b < B) ? cntmat[(size_t)b * P + p] : 0;
        s += v[k];
    }
    int x = s;
    sdata[tid] = x;
    __syncthreads();
    for (int off = 1; off < 256; off <<= 1) {
        int t = (tid >= off) ? sdata[tid - off] : 0;
        __syncthreads();
        x += t;
        sdata[tid] = x;
        __syncthreads();
    }
    int run = x - s;
    #pragma unroll
    for (int k = 0; k < 4; k++) {
        int b = tid * 4 + k;
        if (b < B) cntmat[(size_t)b * P + p] = run;
        run += v[k];
    }
    if (tid == 255) colTotal[p] = x;
}

__global__ __launch_bounds__(256) void totalscanA_kernel(
    const int* __restrict__ colTotal, int* __restrict__ colStart,
    int P, int E) {
    __shared__ int sdata[256];
    int tid = threadIdx.x;
    int v[4];
    int s = 0;
    #pragma unroll
    for (int k = 0; k < 4; k++) {
        int i = tid * 4 + k;
        v[k] = (i < P) ? colTotal[i] : 0;
        s += v[k];
    }
    int x = s;
    sdata[tid] = x;
    __syncthreads();
    for (int off = 1; off < 256; off <<= 1) {
        int t = (tid >= off) ? sdata[tid - off] : 0;
        __syncthreads();
        x += t;
        sdata[tid] = x;
        __syncthreads();
    }
    int run = x - s;
    #pragma unroll
    for (int k = 0; k < 4; k++) {
        int i = tid * 4 + k;
        if (i < P) colStart[i] = run;
        run += v[k];
    }
    if (tid == 0) colStart[P] = E;
}

__global__ __launch_bounds__(512) void scatterA_kernel(
    const int* __restrict__ src, const int* __restrict__ dst,
    const int* __restrict__ cntmat, const int* __restrict__ colStart,
    unsigned* __restrict__ packed, int E, int P) {
    __shared__ int cur[128];
    int tid = threadIdx.x;
    if (tid < P) cur[tid] = colStart[tid] + cntmat[(size_t)blockIdx.x * P + tid];
    __syncthreads();
    int base = blockIdx.x * EPB;
    #pragma unroll
    for (int k = 0; k < EPB; k += 512) {
        int e = base + k + tid;
        if (e < E) {
            int d = dst[e];
            int pos = atomicAdd(&cur[d >> LPBIT], 1);
            packed[pos] = ((unsigned)(d & (PART - 1)) << SRCB) | (unsigned)src[e];
        }
    }
}

// ---------------- Pass C: per-dp counting sort over localdst ----------------

// block = (dp, b): LDS hist over ld of sub-range b; cnt2[dp][ld*BC+b].
__global__ __launch_bounds__(512) void countC_kernel(
    const unsigned* __restrict__ packed, const int* __restrict__ colStart,
    int* __restrict__ cnt2) {
    __shared__ int hist[PART];
    int tid = threadIdx.x;
    int dp = blockIdx.x >> 3, b = blockIdx.x & (BC - 1);
    #pragma unroll
    for (int k = 0; k < PART; k += 512) hist[k + tid] = 0;
    __syncthreads();
    int s0 = colStart[dp], len = colStart[dp + 1] - s0;
    int lo = s0 + (int)(((long long)len * b) / BC);
    int hi = s0 + (int)(((long long)len * (b + 1)) / BC);
    for (int i = lo + tid; i < hi; i += 512)
        atomicAdd(&hist[packed[i] >> SRCB], 1);
    __syncthreads();
    int* row = cnt2 + (size_t)dp * (PART * BC);
    #pragma unroll
    for (int k = 0; k < PART; k += 512)
        row[(k + tid) * BC + b] = hist[k + tid];
}

// One block per dp: exclusive scan of 16384 entries (ld-major, b-minor),
// fold in colStart base; emits rowptr at (ld, b==0) entries.
__global__ __launch_bounds__(512) void scanC_kernel(
    int* __restrict__ cnt2, const int* __restrict__ colStart,
    int* __restrict__ rowptr, int n) {
    __shared__ int sdata[512];
    int dp = blockIdx.x, tid = threadIdx.x;
    int* row = cnt2 + (size_t)dp * (PART * BC);
    int base = colStart[dp];
    int loc[32];
    int s = 0;
    int off = tid * 32;
    #pragma unroll
    for (int k = 0; k < 32; k++) { loc[k] = row[off + k]; s += loc[k]; }
    int x = s;
    sdata[tid] = x;
    __syncthreads();
    for (int o = 1; o < 512; o <<= 1) {
        int t = (tid >= o) ? sdata[tid - o] : 0;
        __syncthreads();
        x += t;
        sdata[tid] = x;
        __syncthreads();
    }
    int run = base + x - s;
    #pragma unroll
    for (int k = 0; k < 32; k++) {
        int idx = off + k;
        row[idx] = run;
        if ((idx & (BC - 1)) == 0) {
            int node = (dp << LPBIT) + (idx >> 3);
            if (node <= n) rowptr[node] = run;
        }
        run += loc[k];
    }
}

// block = (dp, b): scatter sub-range into dst-sorted CSR via LDS cursors.
__global__ __launch_bounds__(512) void scatterC_kernel(
    const unsigned* __restrict__ packed, const int* __restrict__ colStart,
    const int* __restrict__ cnt2, int* __restrict__ srcsorted) {
    __shared__ int cur[PART];
    int tid = threadIdx.x;
    int dp = blockIdx.x >> 3, b = blockIdx.x & (BC - 1);
    const int* row = cnt2 + (size_t)dp * (PART * BC);
    #pragma unroll
    for (int k = 0; k < PART; k += 512) cur[k + tid] = row[(k + tid) * BC + b];
    __syncthreads();
    int s0 = colStart[dp], len = colStart[dp + 1] - s0;
    int lo = s0 + (int)(((long long)len * b) / BC);
    int hi = s0 + (int)(((long long)len * (b + 1)) / BC);
    for (int i = lo + tid; i < hi; i += 512) {
        unsigned w = packed[i];
        int ld = (int)(w >> SRCB);
        int pos = atomicAdd(&cur[ld], 1);
        srcsorted[pos] = (int)(w & ((1u << SRCB) - 1));
    }
}

// ---------------- Node-side (all atomic-free) ----------------

__global__ __launch_bounds__(512) void dinvg_kernel(
    const int* __restrict__ rowptr, const float* __restrict__ x,
    float* __restrict__ dinv, float* __restrict__ g, int n) {
    int i = blockIdx.x * 512 + threadIdx.x;
    if (i >= n) return;
    int deg = rowptr[i + 1] - rowptr[i];
    float d = rsqrtf((float)deg + 1.0f);  // +1 self-loop
    dinv[i] = d;
    float2 xv = ((const float2*)x)[i];
    ((float2*)g)[i] = make_float2(xv.x * d, xv.y * d);
}

// thread = node: gather g[src] (register acc) + fused W1/ReLU/W2 epilogue.
__global__ __launch_bounds__(512) void agg1_kernel(
    const int* __restrict__ rowptr, const int* __restrict__ srcsorted,
    const float* __restrict__ g, const float* __restrict__ dinv,
    const float* __restrict__ W1, const float* __restrict__ b1,
    const float* __restrict__ W2, float* __restrict__ hs2, int n) {
    int i = blockIdx.x * 512 + threadIdx.x;
    if (i >= n) return;
    int p0 = rowptr[i], p1 = rowptr[i + 1];
    const float2* gp = (const float2*)g;
    float s0 = 0.0f, s1 = 0.0f;
    int p = p0;
    for (; p + 4 <= p1; p += 4) {
        int a = srcsorted[p], b = srcsorted[p + 1];
        int c = srcsorted[p + 2], e = srcsorted[p + 3];
        float2 v0 = gp[a], v1 = gp[b], v2 = gp[c], v3 = gp[e];
        s0 += v0.x + v1.x + v2.x + v3.x;
        s1 += v0.y + v1.y + v2.y + v3.y;
    }
    for (; p < p1; p++) {
        float2 v = gp[srcsorted[p]];
        s0 += v.x;
        s1 += v.y;
    }
    float d = dinv[i];
    float2 gi = gp[i];
    s0 = (s0 + gi.x) * d;
    s1 = (s1 + gi.y) * d;
    float h[8];
    #pragma unroll
    for (int f = 0; f < 8; f++)
        h[f] = fmaxf(s0 * W1[f] + s1 * W1[8 + f] + b1[f], 0.0f);
    float oc[4];
    #pragma unroll
    for (int k = 0; k < 4; k++) {
        float a = 0.0f;
        #pragma unroll
        for (int f = 0; f < 8; f++) a += h[f] * W2[4 * f + k];
        oc[k] = a * d;
    }
    float4 o;
    o.x = oc[0]; o.y = oc[1]; o.z = oc[2]; o.w = oc[3];
    *(float4*)(hs2 + 4 * (size_t)i) = o;
}

// thread = node: gather hs2[src] (register acc), write final output.
__global__ __launch_bounds__(512) void agg2_kernel(
    const int* __restrict__ rowptr, const int* __restrict__ srcsorted,
    const float* __restrict__ hs2, const float* __restrict__ dinv,
    const float* __restrict__ b2, float* __restrict__ out, int n) {
    int i = blockIdx.x * 512 + threadIdx.x;
    if (i >= n) return;
    int p0 = rowptr[i], p1 = rowptr[i + 1];
    const float4* hp = (const float4*)hs2;
    float s0 = 0.0f, s1 = 0.0f, s2 = 0.0f, s3 = 0.0f;
    int p = p0;
    for (; p + 4 <= p1; p += 4) {
        int a = srcsorted[p], b = srcsorted[p + 1];
        int c = srcsorted[p + 2], e = srcsorted[p + 3];
        float4 v0 = hp[a], v1 = hp[b], v2 = hp[c], v3 = hp[e];
        s0 += v0.x + v1.x + v2.x + v3.x;
        s1 += v0.y + v1.y + v2.y + v3.y;
        s2 += v0.z + v1.z + v2.z + v3.z;
        s3 += v0.w + v1.w + v2.w + v3.w;
    }
    for (; p < p1; p++) {
        float4 v = hp[srcsorted[p]];
        s0 += v.x; s1 += v.y; s2 += v.z; s3 += v.w;
    }
    float d = dinv[i];
    float4 hi = hp[i];
    float4 o;
    o.x = d * (s0 + hi.x) + b2[0];
    o.y = d * (s1 + hi.y) + b2[1];
    o.z = d * (s2 + hi.z) + b2[2];
    o.w = d * (s3 + hi.w) + b2[3];
    *(float4*)(out + 4 * (size_t)i) = o;
}

extern "C" void kernel_launch(void* const* d_in, const int* in_sizes, int n_in,
                              void* d_out, int out_size, void* d_ws, size_t ws_size,
                              hipStream_t stream) {
    const float* x   = (const float*)d_in[0];
    const int*   ei  = (const int*)d_in[1];
    const float* W1  = (const float*)d_in[2];
    const float* b1  = (const float*)d_in[3];
    const float* W2  = (const float*)d_in[4];
    const float* b2  = (const float*)d_in[5];
    float* out = (float*)d_out;

    const int n = in_sizes[0] / 2;  // x is [N,2]
    const int E = in_sizes[1] / 2;  // edge_index is [2,E]
    const int* src = ei;
    const int* dst = ei + E;

    const int P  = (n + PART - 1) >> LPBIT;  // 98
    const int B1 = (E + EPB - 1) / EPB;      // 782

    int* ws = (int*)d_ws;
    int* colTotal = ws;                                      // 1024
    int* colStart = ws + 1024;                               // 1024
    int* cntmatA  = ws + 2048;                               // B1*P
    size_t cmsz = (((size_t)B1 * P) + 3) & ~(size_t)3;
    int* rowptr = cntmatA + cmsz;                            // n+4
    unsigned* packed = (unsigned*)(rowptr + n + 4);          // E
    int* srcsorted = (int*)(packed + E);                     // E
    int* cnt2 = srcsorted + E;                               // P*PART*BC words
    // cnt2 region reused after pass C (needs 7*nd <= P*PART*BC = 1.6M words):
    size_t nd = (size_t)P << LPBIT;                          // 200704
    float* dinv = (float*)cnt2;                              // nd
    float* g    = dinv + nd;                                 // 2*nd
    float* hs2  = g + 2 * nd;                                // 4*nd

    const int gN = (n + 511) / 512;

    countA_kernel    <<<B1, 512, 0, stream>>>(dst, cntmatA, E, P);
    colscanA_kernel  <<<P, 256, 0, stream>>>(cntmatA, colTotal, B1, P);
    totalscanA_kernel<<<1, 256, 0, stream>>>(colTotal, colStart, P, E);
    scatterA_kernel  <<<B1, 512, 0, stream>>>(src, dst, cntmatA, colStart, packed, E, P);
    countC_kernel    <<<P * BC, 512, 0, stream>>>(packed, colStart, cnt2);
    scanC_kernel     <<<P, 512, 0, stream>>>(cnt2, colStart, rowptr, n);
    scatterC_kernel  <<<P * BC, 512, 0, stream>>>(packed, colStart, cnt2, srcsorted);
    dinvg_kernel     <<<gN, 512, 0, stream>>>(rowptr, x, dinv, g, n);
    agg1_kernel      <<<gN, 512, 0, stream>>>(rowptr, srcsorted, g, dinv, W1, b1, W2, hs2, n);
    agg2_kernel      <<<gN, 512, 0, stream>>>(rowptr, srcsorted, hs2, dinv, b2, out, n);
}